// Round 1
// baseline (289.717 us; speedup 1.0000x reference)
//
#include <hip/hip_runtime.h>
#include <math.h>

#define BB 32
#define TT 48
#define NN 360
#define HH 100
#define DD 64
#define NC 2
#define G4 (4*HH)   // 400

// ---------------- K1: GCN row reduction ----------------
// gout[r] = relu(x[r,:]·w + b), r = b*T*N + t*N + n, row length N=360 (90 float4)
__global__ __launch_bounds__(256) void gcn_kernel(const float* __restrict__ x,
                                                  const float* __restrict__ w,
                                                  const float* __restrict__ bptr,
                                                  float* __restrict__ gout, int nrows) {
    __shared__ __align__(16) float4 w4[90];
    int tid = threadIdx.x;
    if (tid < 90) w4[tid] = ((const float4*)w)[tid];
    __syncthreads();
    float b = bptr[0];
    int lane = tid & 63;
    int wave = tid >> 6;                    // 0..3
    int wavesPerIter = (blockDim.x >> 6) * gridDim.x;
    for (int row = blockIdx.x * (blockDim.x >> 6) + wave; row < nrows; row += wavesPerIter) {
        const float4* xr = (const float4*)(x + (size_t)row * NN);
        float4 xa = xr[lane];
        float4 wa = w4[lane];
        float p = xa.x*wa.x + xa.y*wa.y + xa.z*wa.z + xa.w*wa.w;
        if (lane < 26) {                     // 90 = 64 + 26
            float4 xb = xr[lane + 64];
            float4 wb = w4[lane + 64];
            p += xb.x*wb.x + xb.y*wb.y + xb.z*wb.z + xb.w*wb.w;
        }
        #pragma unroll
        for (int off = 32; off; off >>= 1) p += __shfl_down(p, off, 64);
        if (lane == 0) gout[row] = fmaxf(p + b, 0.f);
    }
}

// ---------------- K2a: transpose W_ih [400,360] -> Wt [360,400] ----------------
__global__ void transpose_wih(const float* __restrict__ Wih, float* __restrict__ Wt) {
    int idx = blockIdx.x * blockDim.x + threadIdx.x;
    if (idx < NN * G4) {
        int n = idx / G4, j = idx % G4;
        Wt[idx] = Wih[j * NN + n];
    }
}

// ---------------- K2: xproj[bt,j] = gout[bt,:]·W_ih[j,:] + b_ih[j]+b_hh[j] ----------------
#define BT_TILE 16
__global__ __launch_bounds__(512) void xproj_kernel(const float* __restrict__ gout,
                                                    const float* __restrict__ Wt,
                                                    const float* __restrict__ b_ih,
                                                    const float* __restrict__ b_hh,
                                                    float* __restrict__ xproj) {
    __shared__ __align__(16) float gt[BT_TILE * NN];   // 23 KB
    int bt0 = blockIdx.x * BT_TILE;
    int tid = threadIdx.x;
    for (int i = tid; i < BT_TILE * NN; i += 512) gt[i] = gout[bt0 * NN + i];
    __syncthreads();
    if (tid < G4) {
        float acc[BT_TILE];
        #pragma unroll
        for (int i = 0; i < BT_TILE; i++) acc[i] = 0.f;
        for (int n = 0; n < NN; n += 4) {
            float w0 = Wt[(n+0)*G4 + tid];
            float w1 = Wt[(n+1)*G4 + tid];
            float w2 = Wt[(n+2)*G4 + tid];
            float w3 = Wt[(n+3)*G4 + tid];
            #pragma unroll
            for (int i = 0; i < BT_TILE; i++) {
                float4 g = *(const float4*)&gt[i*NN + n];
                acc[i] += g.x*w0 + g.y*w1 + g.z*w2 + g.w*w3;
            }
        }
        float bias = b_ih[tid] + b_hh[tid];
        #pragma unroll
        for (int i = 0; i < BT_TILE; i++)
            xproj[(size_t)(bt0 + i) * G4 + tid] = acc[i] + bias;
    }
}

// ---------------- K3: recurrent LSTM, one block per batch element ----------------
__global__ __launch_bounds__(512) void lstm_kernel(const float* __restrict__ xproj,
                                                   const float* __restrict__ Whh,
                                                   float* __restrict__ hs) {
    __shared__ __align__(16) float h_lds[HH];
    __shared__ float gates[G4];
    int b = blockIdx.x;
    int tid = threadIdx.x;
    float wr[HH];
    if (tid < G4) {
        #pragma unroll
        for (int k = 0; k < HH; k++) wr[k] = Whh[tid * HH + k];
    }
    float c = 0.f;
    if (tid < HH) h_lds[tid] = 0.f;
    __syncthreads();
    for (int t = 0; t < TT; t++) {
        if (tid < G4) {
            float g = xproj[(size_t)(b * TT + t) * G4 + tid];
            #pragma unroll
            for (int k = 0; k < HH; k += 4) {
                float4 h4 = *(const float4*)&h_lds[k];
                g += wr[k]*h4.x + wr[k+1]*h4.y + wr[k+2]*h4.z + wr[k+3]*h4.w;
            }
            gates[tid] = g;
        }
        __syncthreads();
        if (tid < HH) {
            float ig = 1.f / (1.f + expf(-gates[tid]));
            float fg = 1.f / (1.f + expf(-gates[tid + HH]));
            float gg = tanhf(gates[tid + 2*HH]);
            float og = 1.f / (1.f + expf(-gates[tid + 3*HH]));
            c = fg * c + ig * gg;
            float hh = og * tanhf(c);
            h_lds[tid] = hh;
            hs[(size_t)(b * TT + t) * HH + tid] = hh;
        }
        __syncthreads();
    }
}

// ---------------- K4: MIL attention + classifier, one block per batch ----------------
__global__ __launch_bounds__(256) void attn_kernel(const float* __restrict__ hs,
                                                   const float* __restrict__ wa1,
                                                   const float* __restrict__ ba1,
                                                   const float* __restrict__ wa2,
                                                   const float* __restrict__ ba2,
                                                   const float* __restrict__ wc,
                                                   const float* __restrict__ bc,
                                                   float* __restrict__ out) {
    __shared__ __align__(16) float ho[TT * HH];   // 19.2 KB
    __shared__ float sc[TT];
    __shared__ float p[TT];
    __shared__ float M[HH];
    int b = blockIdx.x, tid = threadIdx.x;
    for (int i = tid; i < TT * HH; i += 256) ho[i] = hs[(size_t)b * TT * HH + i];
    __syncthreads();
    int wave = tid >> 6, lane = tid & 63;
    for (int t = wave; t < TT; t += 4) {
        float a = 0.f;
        if (lane < DD) {
            float s = ba1[lane];
            for (int h2 = 0; h2 < HH; h2 += 4) {
                float4 h4 = *(const float4*)&ho[t*HH + h2];
                s += wa1[lane*HH + h2]*h4.x + wa1[lane*HH + h2+1]*h4.y
                   + wa1[lane*HH + h2+2]*h4.z + wa1[lane*HH + h2+3]*h4.w;
            }
            a = tanhf(s) * wa2[lane];
        }
        #pragma unroll
        for (int off = 32; off; off >>= 1) a += __shfl_down(a, off, 64);
        if (lane == 0) sc[t] = a + ba2[0];
    }
    __syncthreads();
    if (wave == 0) {
        float v = (lane < TT) ? sc[lane] : -1e30f;
        if (lane < TT) out[BB*NC + b*TT + lane] = v;      // Att (pre-softmax logits)
        float m = v;
        #pragma unroll
        for (int off = 32; off; off >>= 1) m = fmaxf(m, __shfl_xor(m, off, 64));
        float e = (lane < TT) ? expf(v - m) : 0.f;
        float s = e;
        #pragma unroll
        for (int off = 32; off; off >>= 1) s += __shfl_xor(s, off, 64);
        if (lane < TT) p[lane] = e / s;
    }
    __syncthreads();
    if (tid < HH) {
        float m = 0.f;
        for (int t = 0; t < TT; t++) m += p[t] * ho[t*HH + tid];
        M[tid] = m;
    }
    __syncthreads();
    if (tid == 0) {
        float l0 = bc[0], l1 = bc[1];
        for (int h2 = 0; h2 < HH; h2++) { l0 += M[h2]*wc[h2]; l1 += M[h2]*wc[HH + h2]; }
        float mx = fmaxf(l0, l1);
        float e0 = expf(l0 - mx), e1 = expf(l1 - mx);
        float s = e0 + e1;
        out[b*NC + 0] = e0 / s;
        out[b*NC + 1] = e1 / s;
    }
}

extern "C" void kernel_launch(void* const* d_in, const int* in_sizes, int n_in,
                              void* d_out, int out_size, void* d_ws, size_t ws_size,
                              hipStream_t stream) {
    const float* x     = (const float*)d_in[0];
    const float* w_gcn = (const float*)d_in[1];
    const float* b_gcn = (const float*)d_in[2];
    const float* W_ih  = (const float*)d_in[3];
    const float* W_hh  = (const float*)d_in[4];
    const float* b_ih  = (const float*)d_in[5];
    const float* b_hh  = (const float*)d_in[6];
    const float* wa1   = (const float*)d_in[7];
    const float* ba1   = (const float*)d_in[8];
    const float* wa2   = (const float*)d_in[9];
    const float* ba2   = (const float*)d_in[10];
    const float* wc    = (const float*)d_in[11];
    const float* bc    = (const float*)d_in[12];
    float* out = (float*)d_out;
    float* ws  = (float*)d_ws;

    float* gout  = ws;                       // 1536*360   = 552960
    float* Wt    = gout + 552960;            // 360*400    = 144000
    float* xproj = Wt + 144000;              // 1536*400   = 614400
    float* hs    = xproj + 614400;           // 32*48*100  = 153600

    int nrows = BB * TT * NN;                // 552960
    gcn_kernel<<<2048, 256, 0, stream>>>(x, w_gcn, b_gcn, gout, nrows);
    transpose_wih<<<(NN*G4 + 255)/256, 256, 0, stream>>>(W_ih, Wt);
    xproj_kernel<<<(BB*TT)/BT_TILE, 512, 0, stream>>>(gout, Wt, b_ih, b_hh, xproj);
    lstm_kernel<<<BB, 512, 0, stream>>>(xproj, W_hh, hs);
    attn_kernel<<<BB, 256, 0, stream>>>(hs, wa1, ba1, wa2, ba2, wc, bc, out);
}

// Round 2
// 279.253 us; speedup vs baseline: 1.0375x; 1.0375x over previous
//
#include <hip/hip_runtime.h>
#include <math.h>

#define BB 32
#define TT 48
#define NN 360
#define HH 100
#define DD 64
#define NC 2
#define G4 (4*HH)   // 400

__device__ __forceinline__ float sigmoid_fast(float x) {
    return 1.f / (1.f + __expf(-x));
}
__device__ __forceinline__ float tanh_fast(float x) {
    float ax = fabsf(x);
    float e = __expf(-2.f * ax);
    float t = (1.f - e) / (1.f + e);
    return copysignf(t, x);
}

// ---------------- K1: GCN row reduction ----------------
// gout[r] = relu(x[r,:]·w + b), row length N=360 (90 float4)
__global__ __launch_bounds__(256) void gcn_kernel(const float* __restrict__ x,
                                                  const float* __restrict__ w,
                                                  const float* __restrict__ bptr,
                                                  float* __restrict__ gout, int nrows) {
    __shared__ __align__(16) float4 w4[90];
    int tid = threadIdx.x;
    if (tid < 90) w4[tid] = ((const float4*)w)[tid];
    __syncthreads();
    float b = bptr[0];
    int lane = tid & 63;
    int wave = tid >> 6;                    // 0..3
    int wavesPerIter = (blockDim.x >> 6) * gridDim.x;
    for (int row = blockIdx.x * (blockDim.x >> 6) + wave; row < nrows; row += wavesPerIter) {
        const float4* xr = (const float4*)(x + (size_t)row * NN);
        float4 xa = xr[lane];
        float4 wa = w4[lane];
        float p = xa.x*wa.x + xa.y*wa.y + xa.z*wa.z + xa.w*wa.w;
        if (lane < 26) {                     // 90 = 64 + 26
            float4 xb = xr[lane + 64];
            float4 wb = w4[lane + 64];
            p += xb.x*wb.x + xb.y*wb.y + xb.z*wb.z + xb.w*wb.w;
        }
        #pragma unroll
        for (int off = 32; off; off >>= 1) p += __shfl_down(p, off, 64);
        if (lane == 0) gout[row] = fmaxf(p + b, 0.f);
    }
}

// ---------------- K2a: transpose W_ih [400,360] -> Wt [360,400] ----------------
__global__ void transpose_wih(const float* __restrict__ Wih, float* __restrict__ Wt) {
    int idx = blockIdx.x * blockDim.x + threadIdx.x;
    if (idx < NN * G4) {
        int n = idx / G4, j = idx % G4;
        Wt[idx] = Wih[j * NN + n];
    }
}

// ---------------- K2: xproj[bt,j] = gout[bt,:]·W_ih[j,:] + b_ih[j]+b_hh[j] ----------------
// BT2=4 rows per block -> 384 blocks (full CU coverage). g reads are
// uniform-address LDS broadcasts (conflict-free); Wt loads coalesced.
#define BT2 4
__global__ __launch_bounds__(512) void xproj_kernel(const float* __restrict__ gout,
                                                    const float* __restrict__ Wt,
                                                    const float* __restrict__ b_ih,
                                                    const float* __restrict__ b_hh,
                                                    float* __restrict__ xproj) {
    __shared__ __align__(16) float gt[BT2 * NN];   // 5.76 KB
    int bt0 = blockIdx.x * BT2;
    int tid = threadIdx.x;
    for (int i = tid; i < BT2 * NN; i += 512) gt[i] = gout[bt0 * NN + i];
    __syncthreads();
    if (tid < G4) {
        float a0 = 0.f, a1 = 0.f, a2 = 0.f, a3 = 0.f;
        for (int n = 0; n < NN; n += 4) {
            float w0 = Wt[(n+0)*G4 + tid];
            float w1 = Wt[(n+1)*G4 + tid];
            float w2 = Wt[(n+2)*G4 + tid];
            float w3 = Wt[(n+3)*G4 + tid];
            float4 g0 = *(const float4*)&gt[0*NN + n];
            float4 g1 = *(const float4*)&gt[1*NN + n];
            float4 g2 = *(const float4*)&gt[2*NN + n];
            float4 g3 = *(const float4*)&gt[3*NN + n];
            a0 += g0.x*w0 + g0.y*w1 + g0.z*w2 + g0.w*w3;
            a1 += g1.x*w0 + g1.y*w1 + g1.z*w2 + g1.w*w3;
            a2 += g2.x*w0 + g2.y*w1 + g2.z*w2 + g2.w*w3;
            a3 += g3.x*w0 + g3.y*w1 + g3.z*w2 + g3.w*w3;
        }
        float bias = b_ih[tid] + b_hh[tid];
        xproj[(size_t)(bt0 + 0) * G4 + tid] = a0 + bias;
        xproj[(size_t)(bt0 + 1) * G4 + tid] = a1 + bias;
        xproj[(size_t)(bt0 + 2) * G4 + tid] = a2 + bias;
        xproj[(size_t)(bt0 + 3) * G4 + tid] = a3 + bias;
    }
}

// ---------------- K3: fused recurrent LSTM + MIL attention + classifier ----------------
// One block per batch element. h states kept in LDS; attention runs in the
// same block after the time loop (no hs global round-trip).
__global__ __launch_bounds__(512) void lstm_attn_kernel(const float* __restrict__ xproj,
                                                        const float* __restrict__ Whh,
                                                        const float* __restrict__ wa1,
                                                        const float* __restrict__ ba1,
                                                        const float* __restrict__ wa2,
                                                        const float* __restrict__ ba2,
                                                        const float* __restrict__ wc,
                                                        const float* __restrict__ bc,
                                                        float* __restrict__ out) {
    __shared__ __align__(16) float ho[TT * HH];    // 19.2 KB
    __shared__ __align__(16) float h_lds[HH];
    __shared__ float gates[G4];
    __shared__ float sc[TT];
    __shared__ float p[TT];
    __shared__ float M[HH];
    int b = blockIdx.x;
    int tid = threadIdx.x;
    float wr[HH];
    if (tid < G4) {
        #pragma unroll
        for (int k = 0; k < HH; k++) wr[k] = Whh[tid * HH + k];
    }
    float c = 0.f;
    if (tid < HH) h_lds[tid] = 0.f;
    __syncthreads();
    for (int t = 0; t < TT; t++) {
        if (tid < G4) {
            float g = xproj[(size_t)(b * TT + t) * G4 + tid];
            float s0 = 0.f, s1 = 0.f, s2 = 0.f, s3 = 0.f;
            #pragma unroll
            for (int k = 0; k < HH; k += 4) {
                float4 h4 = *(const float4*)&h_lds[k];
                s0 += wr[k+0] * h4.x;
                s1 += wr[k+1] * h4.y;
                s2 += wr[k+2] * h4.z;
                s3 += wr[k+3] * h4.w;
            }
            gates[tid] = g + (s0 + s1) + (s2 + s3);
        }
        __syncthreads();
        if (tid < HH) {
            float ig = sigmoid_fast(gates[tid]);
            float fg = sigmoid_fast(gates[tid + HH]);
            float gg = tanh_fast(gates[tid + 2*HH]);
            float og = sigmoid_fast(gates[tid + 3*HH]);
            c = fg * c + ig * gg;
            float hh = og * tanh_fast(c);
            h_lds[tid] = hh;
            ho[t * HH + tid] = hh;
        }
        __syncthreads();
    }
    // ---- MIL attention ----
    int wave = tid >> 6, lane = tid & 63;
    for (int t = wave; t < TT; t += 8) {
        float a = 0.f;
        if (lane < DD) {
            float s = ba1[lane];
            #pragma unroll
            for (int h2 = 0; h2 < HH; h2 += 4) {
                float4 h4 = *(const float4*)&ho[t*HH + h2];
                s += wa1[lane*HH + h2+0]*h4.x + wa1[lane*HH + h2+1]*h4.y
                   + wa1[lane*HH + h2+2]*h4.z + wa1[lane*HH + h2+3]*h4.w;
            }
            a = tanh_fast(s) * wa2[lane];
        }
        #pragma unroll
        for (int off = 32; off; off >>= 1) a += __shfl_down(a, off, 64);
        if (lane == 0) sc[t] = a + ba2[0];
    }
    __syncthreads();
    if (tid < 64) {
        float v = (lane < TT) ? sc[lane] : -1e30f;
        if (lane < TT) out[BB*NC + b*TT + lane] = v;      // Att (pre-softmax logits)
        float m = v;
        #pragma unroll
        for (int off = 32; off; off >>= 1) m = fmaxf(m, __shfl_xor(m, off, 64));
        float e = (lane < TT) ? __expf(v - m) : 0.f;
        float s = e;
        #pragma unroll
        for (int off = 32; off; off >>= 1) s += __shfl_xor(s, off, 64);
        if (lane < TT) p[lane] = e / s;
    }
    __syncthreads();
    if (tid < HH) {
        float m = 0.f;
        #pragma unroll
        for (int t = 0; t < TT; t++) m += p[t] * ho[t*HH + tid];
        M[tid] = m;
    }
    __syncthreads();
    if (tid == 0) {
        float l0 = bc[0], l1 = bc[1];
        for (int h2 = 0; h2 < HH; h2++) { l0 += M[h2]*wc[h2]; l1 += M[h2]*wc[HH + h2]; }
        float mx = fmaxf(l0, l1);
        float e0 = __expf(l0 - mx), e1 = __expf(l1 - mx);
        float s = e0 + e1;
        out[b*NC + 0] = e0 / s;
        out[b*NC + 1] = e1 / s;
    }
}

extern "C" void kernel_launch(void* const* d_in, const int* in_sizes, int n_in,
                              void* d_out, int out_size, void* d_ws, size_t ws_size,
                              hipStream_t stream) {
    const float* x     = (const float*)d_in[0];
    const float* w_gcn = (const float*)d_in[1];
    const float* b_gcn = (const float*)d_in[2];
    const float* W_ih  = (const float*)d_in[3];
    const float* W_hh  = (const float*)d_in[4];
    const float* b_ih  = (const float*)d_in[5];
    const float* b_hh  = (const float*)d_in[6];
    const float* wa1   = (const float*)d_in[7];
    const float* ba1   = (const float*)d_in[8];
    const float* wa2   = (const float*)d_in[9];
    const float* ba2   = (const float*)d_in[10];
    const float* wc    = (const float*)d_in[11];
    const float* bc    = (const float*)d_in[12];
    float* out = (float*)d_out;
    float* ws  = (float*)d_ws;

    float* gout  = ws;                       // 1536*360   = 552960
    float* Wt    = gout + 552960;            // 360*400    = 144000
    float* xproj = Wt + 144000;              // 1536*400   = 614400

    int nrows = BB * TT * NN;                // 552960
    transpose_wih<<<(NN*G4 + 255)/256, 256, 0, stream>>>(W_ih, Wt);
    gcn_kernel<<<2048, 256, 0, stream>>>(x, w_gcn, b_gcn, gout, nrows);
    xproj_kernel<<<(BB*TT)/BT2, 512, 0, stream>>>(gout, Wt, b_ih, b_hh, xproj);
    lstm_attn_kernel<<<BB, 512, 0, stream>>>(xproj, W_hh, wa1, ba1, wa2, ba2, wc, bc, out);
}